// Round 10
// baseline (328.393 us; speedup 1.0000x reference)
//
#include <hip/hip_runtime.h>
#include <hip/hip_bf16.h>

typedef short short8 __attribute__((ext_vector_type(8)));
typedef float f32x16 __attribute__((ext_vector_type(16)));
typedef float f32x4 __attribute__((ext_vector_type(4)));

#define BM 128
#define BN 128

typedef const __attribute__((address_space(1))) void gas_t;
typedef __attribute__((address_space(3))) void las_t;

__device__ __forceinline__ unsigned short f2bf(float f) {
  unsigned int u = __float_as_uint(f);
  u += 0x7FFFu + ((u >> 16) & 1u);   // round-to-nearest-even
  return (unsigned short)(u >> 16);
}

// packed max of two u32s holding 2x u16 (bf16 bit-order == numeric order for >=0)
__device__ __forceinline__ unsigned int pmaxu16(unsigned int a, unsigned int b) {
  unsigned int lo = ((a & 0xFFFFu) > (b & 0xFFFFu)) ? (a & 0xFFFFu) : (b & 0xFFFFu);
  unsigned int hi = ((a >> 16) > (b >> 16)) ? (a & 0xFFFF0000u) : (b & 0xFFFF0000u);
  return lo | hi;
}

// tanh via single v_exp_f32 + v_rcp_f32: tanh(x) = 1 - 2/(e^2x + 1).
__device__ __forceinline__ float fast_tanh(float x) {
  x = fminf(fmaxf(x, -10.f), 10.f);
  float t = __builtin_amdgcn_exp2f(x * 2.8853900817779268f);  // 2*log2(e)
  return 1.f - 2.f * __builtin_amdgcn_rcpf(t + 1.f);
}

struct GemmP {
  const unsigned short* A;
  const unsigned short* Bm;
  void* C;
  const float* A2f;            // second A source for k >= kSplit: bf16 head-planes, max-reduced during staging
  // alt pointer set for merged launches: used when z >= zSplit
  const unsigned short* A_b;
  const unsigned short* Bm_b;
  void* C_b;
  const float* A2f_b;
  const float* mask_p;
  const float* mask_s;
  const float* bias;
  const float* bias_b;
  long long sAb, sAh, sBb, sBh, sCb, sCh;
  int lda, lda2, ldb, ldc, M, N, K, Hh, kSplit, zSplit, nbx, nby;
};

// ---------------------------------------------------------------------------
// Legacy 128x128 / 256-thread kernel (step 4 wp-part and step 5).
// TA: 0 = A is M x K row-major (lds-DMA staging, pitch 32); 1 = A stored K x M.
// EPI: 0 bf16 store; 1 tanh*mask bf16; 3 +bias,relu f32; 4 relu bf16 plane store.
// kSplit phase-2: A2f = 8 relu'd bf16 head-planes [b*8+h][512][128]; staging
// does the head-max in-register (integer max, bit-identical to pooled bf16).
template <int TA, int EPI>
__device__ __forceinline__ void gemm_body(const GemmP& p, int bx, int by, int bz, char* smem_) {
  constexpr int PA = (TA == 0) ? 32 : 40;
  constexpr int HSA = (TA == 0) ? 4096 : 5120;  // shorts per A half-tile
  unsigned short* As = (unsigned short*)smem_;
  unsigned short* Bs = (unsigned short*)(smem_ + 2 * HSA * 2);

  int z = bz;
  const unsigned short* Abase = p.A;
  const unsigned short* Bbase = p.Bm;
  void* Cvp = p.C;
  const float* A2f = p.A2f;
  const float* bias = p.bias;
  if (p.zSplit && z >= p.zSplit) {
    z -= p.zSplit;
    Abase = p.A_b; Bbase = p.Bm_b; Cvp = p.C_b; A2f = p.A2f_b; bias = p.bias_b;
  }
  const int zb = z / p.Hh, zh = z % p.Hh;
  const unsigned short* A = Abase + (size_t)zb * p.sAb + (size_t)zh * p.sAh;
  const unsigned short* B = Bbase + (size_t)zb * p.sBb + (size_t)zh * p.sBh;
  const int m0 = bx * BM, n0 = by * BN;
  const int tid = threadIdx.x;
  const int wid = tid >> 6, lane = tid & 63;
  const int wm = (wid >> 1) * 64, wn = (wid & 1) * 64;
  const int lrow = lane & 31;          // row within 32x32 frag
  const int lk8 = (lane >> 5) * 8;     // k-offset within 16-k chunk

  f32x16 acc[2][2] = {};

  const int dm = tid >> 2, dkg = tid & 3;

  auto mfma_block = [&]() {
#pragma unroll
    for (int h = 0; h < 2; ++h)
#pragma unroll
      for (int kc = 0; kc < 2; ++kc) {
        short8 af[2], bfv[2];
#pragma unroll
        for (int mt = 0; mt < 2; ++mt)
          af[mt] = *(const short8*)&As[h * HSA + (wm + mt * 32 + lrow) * PA + kc * 16 + lk8];
#pragma unroll
        for (int nt = 0; nt < 2; ++nt)
          bfv[nt] = *(const short8*)&Bs[h * 4096 + (wn + nt * 32 + lrow) * 32 + kc * 16 + lk8];
#pragma unroll
        for (int mt = 0; mt < 2; ++mt)
#pragma unroll
          for (int nt = 0; nt < 2; ++nt)
            acc[mt][nt] = __builtin_amdgcn_mfma_f32_32x32x16_bf16(af[mt], bfv[nt], acc[mt][nt], 0, 0, 0);
      }
  };
  auto stage_b = [&](int k0) {
#pragma unroll
    for (int h = 0; h < 2; ++h)
#pragma unroll
      for (int q = 0; q < 2; ++q) {
        const unsigned short* src = B + (size_t)(n0 + q * 64 + dm) * p.ldb + (k0 + h * 32 + dkg * 8);
        __builtin_amdgcn_global_load_lds((gas_t*)src,
                                         (las_t*)&Bs[h * 4096 + q * 2048 + wid * 512],
                                         16, 0, 0);
      }
  };

  const int nIter = p.K >> 6;
  const int nIter1 = p.kSplit ? (p.kSplit >> 6) : nIter;

  for (int it = 0; it < nIter1; ++it) {
    const int k0 = it << 6;
    if (TA == 0) {
#pragma unroll
      for (int h = 0; h < 2; ++h)
#pragma unroll
        for (int q = 0; q < 2; ++q) {
          const unsigned short* src = A + (size_t)(m0 + q * 64 + dm) * p.lda + (k0 + h * 32 + dkg * 8);
          __builtin_amdgcn_global_load_lds((gas_t*)src,
                                           (las_t*)&As[h * HSA + q * 2048 + wid * 512],
                                           16, 0, 0);
        }
    } else {
      const int kk = tid & 31, mg = (tid >> 5) << 4;
#pragma unroll
      for (int h = 0; h < 2; ++h) {
        const unsigned short* src = A + (size_t)(k0 + h * 32 + kk) * p.lda + (m0 + mg);
        uint4 v0 = *(const uint4*)src;
        uint4 v1 = *(const uint4*)(src + 8);
        unsigned short tmp[16];
        *(uint4*)&tmp[0] = v0;
        *(uint4*)&tmp[8] = v1;
#pragma unroll
        for (int j = 0; j < 16; ++j) As[h * HSA + (mg + j) * PA + kk] = tmp[j];
      }
    }
    stage_b(k0);
    __syncthreads();
    mfma_block();
    __syncthreads();
  }

  // phase 2 (TA=0, step 5): A from 8 relu'd bf16 head-planes with in-register
  // head-max during staging (integer max on non-negative bf16 == float max;
  // bit-identical to the old f32 pool + reduce_k pass).
  if (TA == 0 && p.kSplit) {
    const unsigned short* planes = (const unsigned short*)A2f;  // [b*8+h][512][128]
    for (int it = nIter1; it < nIter; ++it) {
      const int k0 = it << 6;
#pragma unroll
      for (int h2 = 0; h2 < 2; ++h2) {
        const int ko = k0 + h2 * 32 - p.kSplit;   // 0..127 within plane
#pragma unroll
        for (int q = 0; q < 2; ++q) {
          const int row = m0 + q * 64 + dm;       // = b*512 + x
          const unsigned int* s0 = (const unsigned int*)(planes
              + ((size_t)(((row >> 9) << 12) + (row & 511)) * 128 + ko + dkg * 8));
          uint4 mv = *(const uint4*)s0;
#pragma unroll
          for (int hh = 1; hh < 8; ++hh) {
            uint4 v = *(const uint4*)(s0 + (size_t)hh * 32768);   // head stride 512*128 shorts
            mv.x = pmaxu16(mv.x, v.x);
            mv.y = pmaxu16(mv.y, v.y);
            mv.z = pmaxu16(mv.z, v.z);
            mv.w = pmaxu16(mv.w, v.w);
          }
          *(uint4*)&As[h2 * HSA + (q * 64 + dm) * 32 + dkg * 8] = mv;
        }
      }
      stage_b(k0);
      __syncthreads();
      mfma_block();
      __syncthreads();
    }
  }

  unsigned short* Cu = (unsigned short*)Cvp + (size_t)zb * p.sCb + (size_t)zh * p.sCh;
  float* Cf = (float*)Cvp + (size_t)zb * p.sCb + (size_t)zh * p.sCh;

  const int rbase = 4 * (lane >> 5);

  float mp[2][16], ms[2];
  if constexpr (EPI == 1) {
#pragma unroll
    for (int mt = 0; mt < 2; ++mt)
#pragma unroll
      for (int reg = 0; reg < 16; ++reg) {
        const int rl = (reg & 3) + 8 * (reg >> 2) + rbase;
        mp[mt][reg] = p.mask_p[(size_t)zb * p.M + (m0 + wm + mt * 32 + rl)];
      }
#pragma unroll
    for (int nt = 0; nt < 2; ++nt)
      ms[nt] = p.mask_s[(size_t)zb * p.N + (n0 + wn + nt * 32 + lrow)];
  }
  if constexpr (EPI == 3) {
#pragma unroll
    for (int nt = 0; nt < 2; ++nt)
      ms[nt] = bias[n0 + wn + nt * 32 + lrow];
  }

#pragma unroll
  for (int mt = 0; mt < 2; ++mt) {
#pragma unroll
    for (int nt = 0; nt < 2; ++nt) {
      f32x16 a = acc[mt][nt];
#pragma unroll
      for (int reg = 0; reg < 16; ++reg) {
        const int rl = (reg & 3) + 8 * (reg >> 2) + rbase;
        const int grow = m0 + wm + mt * 32 + rl;
        const int gcol = n0 + wn + nt * 32 + lrow;
        const size_t idx = (size_t)grow * p.ldc + gcol;
        const float v = a[reg];
        if constexpr (EPI == 0) {
          Cu[idx] = f2bf(v);
        } else if constexpr (EPI == 1) {
          Cu[idx] = f2bf(fast_tanh(v) * (mp[mt][reg] * ms[nt]));
        } else if constexpr (EPI == 3) {
          Cf[idx] = fmaxf(v + ms[nt], 0.f);
        } else {
          // EPI == 4: relu, bf16 per-head plane store (head-max during step-5 staging)
          Cu[idx] = f2bf(fmaxf(v, 0.f));
        }
      }
    }
  }
}

template <int TA, int EPI>
__global__ __launch_bounds__(256) void gemm_k(GemmP p) {
  extern __shared__ char smem[];
  gemm_body<TA, EPI>(p, blockIdx.x, blockIdx.y, blockIdx.z, smem);
}

// ---------------------------------------------------------------------------
// gemm17: 256x128 tile / 256 threads / B-from-global — LDS-port-relief design.
// r8 post-mortem: at a 64x64 wave tile the LDS read port (3840 cyc/CU/tile) exceeds
// the MFMA pipe (3725) -> every config was LDS-port- or drain-bound at 33%.
// gemm17: 4 waves as 2(M) x 2(N), wave tile 128x64 (MFMA/LDS ratio 1.07), and
// B-fragments read STRAIGHT FROM GLOBAL (weight panel is L2-resident; the frag
// read = 16 contiguous 64-B lines per wave-instr). LDS holds A only:
// 2-slot double buffer (2 x 32 KB), distance-1 prefetch, counted vmcnt(8) +
// one raw s_barrier per K-tile — NO drain-0 in the main loop (T4).
// Audit (r9 rerun): vmcnt retires in issue order -> queue [stageA(t)x8][bq(t)x8],
// vmcnt(8) == stageA(t) complete; slot (t+1)&1 overwrite is safe because every
// wave's ds_reads of that slot completed (lgkmcnt before MFMA) before it reached
// iteration t's barrier; all fragment addresses bounds-checked per launch config.
// Per-CU per K-tile at 2 blocks: MFMA 2483 cyc vs LDS port 1792 -> MFMA-bound.
// __launch_bounds__(256,2): reg cap 256 >= acc(128)+~96 arch (r7-proven budget).
// EPI: 0 = bf16 store; 1 = tanh*mask bf16; 4 = relu bf16 plane store.
template <int EPI>
__device__ __forceinline__ void gemm17_body(const GemmP& p, int bx, int by, int bz, char* smem_) {
  int z = bz;
  const unsigned short* Abase = p.A;
  const unsigned short* Bbase = p.Bm;
  void* Cvp = p.C;
  if (p.zSplit && z >= p.zSplit) {
    z -= p.zSplit;
    Abase = p.A_b; Bbase = p.Bm_b; Cvp = p.C_b;
  }
  const int zb = z / p.Hh, zh = z % p.Hh;
  const unsigned short* A = Abase + (size_t)zb * p.sAb + (size_t)zh * p.sAh;
  const unsigned short* B = Bbase + (size_t)zb * p.sBb + (size_t)zh * p.sBh;
  const int m0 = bx * 256, n0 = by * 128;
  const int tid = threadIdx.x;
  const int wid = tid >> 6, lane = tid & 63;
  const int wm = wid >> 1, wn = wid & 1;        // 2 x 2 wave grid, wave tile 128x64
  const int lrow = lane & 15, lhi = lane >> 4;  // MFMA 16x16x32 lane decomposition

  // A staging source coords: LDS linear dest byte (seg s: s*4096 + tid*16) ->
  // row = s*32 + tid/8, col bytes = (tid&7)*16; source col = dest col ^ ((row&7)<<4)
  const int rr = tid >> 3;                              // 0..31
  const int cs = ((tid & 7) * 8) ^ ((rr & 7) << 3);     // source col, shorts

  // A read offsets (swizzled; row&7 == lrow&7 since frag rows are 16-aligned)
  const int colx = (lhi * 16) ^ ((lrow & 7) << 4);
  const int offA = (wm * 128 + lrow) * 128 + colx;

  // B fragment row base in global: row n0 + wn*64 + fn*16 + lrow, k-col lhi*8 shorts
  const unsigned short* Brow = B + (size_t)(n0 + wn * 64 + lrow) * p.ldb + lhi * 8;

  f32x4 acc[8][4] = {};

  auto stageA = [&](int t, int slot) {
    const int k0 = t << 6;
    const unsigned short* sa = A + (size_t)(m0 + rr) * p.lda + k0 + cs;
#pragma unroll
    for (int s = 0; s < 8; ++s)
      __builtin_amdgcn_global_load_lds((gas_t*)(sa + (size_t)(s * 32) * p.lda),
                                       (las_t*)(smem_ + slot * 32768 + s * 4096 + tid * 16),
                                       16, 0, 0);
  };

  const int nt = p.K >> 6;   // K-tiles of 64
  stageA(0, 0);

  for (int t = 0; t < nt; ++t) {
    const int k0 = t << 6;

    // ---- B fragments for tile t, straight from global (L2) ----
    short8 bq[2][4];
#pragma unroll
    for (int ks = 0; ks < 2; ++ks)
#pragma unroll
      for (int fn = 0; fn < 4; ++fn)
        bq[ks][fn] = *(const short8*)(Brow + (size_t)(fn * 16) * p.ldb + k0 + ks * 32);

    // ---- counted wait: oldest 8 outstanding = A-stage(t); never drain-0 ----
    asm volatile("s_waitcnt vmcnt(8)" ::: "memory");
    __builtin_amdgcn_s_barrier();
    __builtin_amdgcn_sched_barrier(0);

    // issue next A-tile into the other slot (all waves past prior reads of it)
    if (t + 1 < nt) stageA(t + 1, (t + 1) & 1);

    const char* sb = smem_ + (t & 1) * 32768;
#pragma unroll
    for (int ks = 0; ks < 2; ++ks) {
#pragma unroll
      for (int mh = 0; mh < 2; ++mh) {
        short8 af[4];
#pragma unroll
        for (int fm = 0; fm < 4; ++fm)
          af[fm] = *(const short8*)(sb + (offA ^ (ks * 64)) + (mh * 4 + fm) * 2048);
        __builtin_amdgcn_s_setprio(1);
#pragma unroll
        for (int fm = 0; fm < 4; ++fm)
#pragma unroll
          for (int fn = 0; fn < 4; ++fn)
            acc[mh * 4 + fm][fn] =
                __builtin_amdgcn_mfma_f32_16x16x32_bf16(af[fm], bq[ks][fn], acc[mh * 4 + fm][fn], 0, 0, 0);
        __builtin_amdgcn_s_setprio(0);
      }
    }
  }

  // ---- epilogue ----
  unsigned short* Cu = (unsigned short*)Cvp + (size_t)zb * p.sCb + (size_t)zh * p.sCh;

  float ms[4];
  if constexpr (EPI == 1) {
#pragma unroll
    for (int fn = 0; fn < 4; ++fn)
      ms[fn] = p.mask_s[(size_t)zb * p.N + (n0 + wn * 64 + fn * 16 + lrow)];
  }

#pragma unroll
  for (int fm = 0; fm < 8; ++fm)
#pragma unroll
    for (int fn = 0; fn < 4; ++fn) {
      f32x4 a = acc[fm][fn];
      const int gcol = n0 + wn * 64 + fn * 16 + lrow;
#pragma unroll
      for (int reg = 0; reg < 4; ++reg) {
        const int grow = m0 + wm * 128 + fm * 16 + lhi * 4 + reg;
        const size_t idx = (size_t)grow * p.ldc + gcol;
        if constexpr (EPI == 0) {
          Cu[idx] = f2bf(a[reg]);
        } else if constexpr (EPI == 4) {
          Cu[idx] = f2bf(fmaxf(a[reg], 0.f));
        } else {
          const float mp = p.mask_p[(size_t)zb * p.M + grow];
          Cu[idx] = f2bf(fast_tanh(a[reg]) * (mp * ms[fn]));
        }
      }
    }
}

template <int EPI>
__global__ __launch_bounds__(256, 2) void gemm17_k(GemmP p) {
  extern __shared__ char smem[];
  gemm17_body<EPI>(p, blockIdx.x, blockIdx.y, blockIdx.z, smem);
}

template <int E1, int E2>
__global__ __launch_bounds__(256, 2) void gemm17_pair_k(GemmP a, GemmP b, int nA) {
  extern __shared__ char smem[];
  int bid = blockIdx.x;
  if (bid < nA) {
    const int per = a.nbx * a.nby;
    const int z = bid / per, r = bid % per;
    gemm17_body<E1>(a, r % a.nbx, r / a.nbx, z, smem);
  } else {
    bid -= nA;
    const int per = b.nbx * b.nby;
    const int z = bid / per, r = bid % per;
    gemm17_body<E2>(b, r % b.nbx, r / b.nbx, z, smem);
  }
}

// ---- fused preamble: input cvt, 4 weight transposes ----
__device__ __forceinline__ void trans_body(const float* src, unsigned short* dst,
                                           int R, int C, int bx, int by, float (*tile)[33]) {
  const int r0 = by * 32, c0 = bx * 32;
  const int tx = threadIdx.x & 31, ty = threadIdx.x >> 5;  // 32 x 8
#pragma unroll
  for (int j = 0; j < 4; ++j)
    tile[ty + j * 8][tx] = src[(size_t)(r0 + ty + j * 8) * C + (c0 + tx)];
  __syncthreads();
#pragma unroll
  for (int j = 0; j < 4; ++j)
    dst[(size_t)(c0 + ty + j * 8) * R + (r0 + tx)] = f2bf(tile[tx][ty + j * 8]);
}

__global__ __launch_bounds__(256) void prep_k(const float* P, const float* S,
                                              unsigned short* Pbf, unsigned short* Sbf,
                                              const float* W_aff, unsigned short* WaT,
                                              const float* W_p, unsigned short* WpT,
                                              const float* W_s, unsigned short* WsT,
                                              const float* W_fp, unsigned short* WfpT,
                                              const float* W_fs, unsigned short* WfsT) {
  __shared__ float tile[32][33];
  const int bid = blockIdx.x;
  if (bid < 8192) {
    const int n4 = 1048576;  // 16*512*512/4
    int i = bid * 256 + threadIdx.x;
    const float4* s = (const float4*)P;
    ushort4* d = (ushort4*)Pbf;
    if (i >= n4) { i -= n4; s = (const float4*)S; d = (ushort4*)Sbf; }
    float4 v = s[i];
    ushort4 o;
    o.x = f2bf(v.x); o.y = f2bf(v.y); o.z = f2bf(v.z); o.w = f2bf(v.w);
    d[i] = o;
  } else if (bid < 10240) {
    const int l = bid - 8192;                      // 16x16 tiles x 8 heads
    const int z = l >> 8, r = l & 255;
    trans_body(W_aff + (size_t)z * 262144, WaT + (size_t)z * 262144, 512, 512,
               r & 15, r >> 4, tile);
  } else if (bid < 11264) {
    const int l = bid - 10240;                     // 32x16 tiles x 2
    const int z = l >> 9, r = l & 511;
    trans_body(z ? W_s : W_p, z ? WsT : WpT, 512, 1024, r & 31, r >> 5, tile);
  } else {
    const int l = bid - 11264;                     // 16x20 tiles x 2
    const int z = l / 320, r = l % 320;
    trans_body(z ? W_fs : W_fp, z ? WfsT : WfpT, 640, 512, r & 15, r >> 4, tile);
  }
}

extern "C" void kernel_launch(void* const* d_in, const int* in_sizes, int n_in,
                              void* d_out, int out_size, void* d_ws, size_t ws_size,
                              hipStream_t stream) {
  (void)in_sizes; (void)n_in; (void)out_size; (void)ws_size;
  const float* primary   = (const float*)d_in[0];
  const float* secondary = (const float*)d_in[1];
  const float* pmask     = (const float*)d_in[2];
  const float* smask     = (const float*)d_in[3];
  const float* W_aff     = (const float*)d_in[4];
  const float* W_p       = (const float*)d_in[5];
  const float* W_s       = (const float*)d_in[6];
  const float* W_fp      = (const float*)d_in[7];
  const float* b_fp      = (const float*)d_in[8];
  const float* W_fs      = (const float*)d_in[9];
  const float* b_fs      = (const float*)d_in[10];

  constexpr int Bb = 16, L = 512, Dd = 512, Hh = 8, HDd = 128, INNER = 1024, CAT = 640;
  constexpr int NT = Hh * Dd;                      // 4096
  constexpr long long LD = (long long)L * Dd;      // 262144
  constexpr long long LL = (long long)L * L;       // 262144

  // one-time: allow 64 KiB dynamic LDS on the gemm17-family kernels
  static bool s_attr = [] {
    hipFuncSetAttribute(reinterpret_cast<const void*>(&gemm17_pair_k<0, 0>),
                        hipFuncAttributeMaxDynamicSharedMemorySize, 65536);
    hipFuncSetAttribute(reinterpret_cast<const void*>(&gemm17_k<1>),
                        hipFuncAttributeMaxDynamicSharedMemorySize, 65536);
    hipFuncSetAttribute(reinterpret_cast<const void*>(&gemm17_k<4>),
                        hipFuncAttributeMaxDynamicSharedMemorySize, 65536);
    return true;
  }();
  (void)s_attr;

  char* base = (char*)d_ws;
  size_t off = 0;
  auto alloc = [&](size_t bytes) -> void* {
    void* r = base + off;
    off += (bytes + 255) & ~(size_t)255;
    return r;
  };

  unsigned short* Pbf   = (unsigned short*)alloc((size_t)Bb * L * Dd * 2);
  unsigned short* Sbf   = (unsigned short*)alloc((size_t)Bb * L * Dd * 2);
  unsigned short* WaT   = (unsigned short*)alloc((size_t)NT * Dd * 2);        // [h*512+f][e]
  unsigned short* WpT   = (unsigned short*)alloc((size_t)INNER * Dd * 2);     // [n][e]
  unsigned short* WsT   = (unsigned short*)alloc((size_t)INNER * Dd * 2);
  unsigned short* WfpT  = (unsigned short*)alloc((size_t)Dd * CAT * 2);       // [n][k]
  unsigned short* WfsT  = (unsigned short*)alloc((size_t)Dd * CAT * 2);
  unsigned short* psT   = (unsigned short*)alloc((size_t)Bb * INNER * L * 2); // [b][d][j]
  unsigned short* ppT   = (unsigned short*)alloc((size_t)Bb * INNER * L * 2); // [b][d][i]
  unsigned short* Tbuf  = (unsigned short*)alloc((size_t)Bb * L * NT * 2);    // [b*L+i][h*512+f]
  unsigned short* affb  = (unsigned short*)alloc((size_t)Bb * Hh * L * L * 2);

  // per-head relu'd planes (step 4 output): alias onto Tbuf (dead after step 3).
  // ws: [b][h][i][d] 16.8 MB ; wp: [b][h][j][d] 16.8 MB ; Tbuf is 64 MB.
  unsigned short* wsBuf = Tbuf;
  unsigned short* wpBuf = Tbuf + (size_t)Bb * Hh * L * HDd;

  // ---- 1) fused preamble ----
  prep_k<<<dim3(11904), dim3(256), 0, stream>>>(primary, secondary, Pbf, Sbf,
                                                W_aff, WaT, W_p, WpT, W_s, WsT,
                                                W_fp, WfpT, W_fs, WfsT);

  // ---- 2) Tbuf = P @ Waff(stacked)  ||  psT/ppT = (S@W_s)^T / (P@W_p)^T ----
  // gemm17: 256x128, 256 threads, A-only dbuf LDS, counted vmcnt, 2 blocks/CU
  {
    GemmP a{};
    a.A = Pbf; a.lda = Dd;
    a.Bm = WaT; a.ldb = Dd;
    a.C = Tbuf; a.ldc = NT;
    a.M = Bb * L; a.N = NT; a.K = Dd; a.Hh = 1; a.nbx = 32; a.nby = 32;

    GemmP b{};
    b.A = WsT; b.lda = Dd; b.sAb = 0;
    b.Bm = Sbf; b.ldb = Dd; b.sBb = LD;
    b.C = psT; b.ldc = L; b.sCb = (long long)INNER * L;
    b.A_b = WpT; b.Bm_b = Pbf; b.C_b = ppT;
    b.M = INNER; b.N = L; b.K = Dd; b.Hh = 1; b.zSplit = Bb; b.nbx = 4; b.nby = 4;

    gemm17_pair_k<0, 0><<<dim3(1024 + 512), dim3(256), 65536, stream>>>(a, b, 1024);
  }

  // ---- 3) aff[b,h] = tanh(T[b,h] @ S_b^T) * mask ----
  {
    GemmP g{};
    g.A = Tbuf; g.lda = NT; g.sAb = (long long)L * NT; g.sAh = Dd;
    g.Bm = Sbf; g.ldb = Dd; g.sBb = LD; g.sBh = 0;
    g.C = affb; g.ldc = L; g.sCb = (long long)Hh * LL; g.sCh = LL;
    g.mask_p = pmask; g.mask_s = smask;
    g.M = L; g.N = L; g.K = Dd; g.Hh = Hh;
    gemm17_k<1><<<dim3(2, 4, Bb * Hh), dim3(256), 65536, stream>>>(g);
  }

  // ---- 4a) ws = relu(aff @ psT^T) via gemm17 (fast A path) ----
  {
    GemmP a{};                       // ws: M=512(i), N=128(d), K=512(j) per (b,h)
    a.A = affb; a.lda = L; a.sAb = (long long)Hh * LL; a.sAh = LL;
    a.Bm = psT; a.ldb = L; a.sBb = (long long)INNER * L; a.sBh = (long long)HDd * L;
    a.C = wsBuf; a.ldc = HDd; a.sCb = (long long)Hh * L * HDd; a.sCh = (long long)L * HDd;
    a.M = L; a.N = HDd; a.K = L; a.Hh = Hh;
    gemm17_k<4><<<dim3(2, 1, Bb * Hh), dim3(256), 65536, stream>>>(a);
  }

  // ---- 4b) wp = relu(aff^T @ ppT^T) via legacy TA=1 (VALU-transpose A) ----
  {
    GemmP b{};
    b.A = affb; b.lda = L; b.sAb = (long long)Hh * LL; b.sAh = LL;
    b.Bm = ppT; b.ldb = L; b.sBb = (long long)INNER * L; b.sBh = (long long)HDd * L;
    b.C = wpBuf; b.ldc = HDd; b.sCb = (long long)Hh * L * HDd; b.sCh = (long long)L * HDd;
    b.M = L; b.N = HDd; b.K = L; b.Hh = Hh;
    gemm_k<1, 4><<<dim3(4, 1, Bb * Hh), dim3(256), 36864, stream>>>(b);
  }

  // ---- 5) merged output FFNs; A2 = bf16 head-planes, head-max during staging ----
  {
    GemmP g{};
    g.A = Pbf; g.lda = Dd;
    g.A2f = (const float*)wsBuf; g.lda2 = HDd; g.kSplit = Dd;
    g.Bm = WfpT; g.ldb = CAT;
    g.C = d_out; g.ldc = Dd;
    g.bias = b_fp;
    g.A_b = Sbf; g.A2f_b = (const float*)wpBuf; g.Bm_b = WfsT;
    g.C_b = (float*)d_out + (size_t)Bb * L * Dd;
    g.bias_b = b_fs;
    g.M = Bb * L; g.N = Dd; g.K = CAT; g.Hh = 1; g.zSplit = 1;
    gemm_k<0, 3><<<dim3(64, 4, 2), dim3(256), 32768, stream>>>(g);
  }
}

// Round 11
// 297.292 us; speedup vs baseline: 1.1046x; 1.1046x over previous
//
#include <hip/hip_runtime.h>
#include <hip/hip_bf16.h>

typedef short short8 __attribute__((ext_vector_type(8)));
typedef float f32x16 __attribute__((ext_vector_type(16)));
typedef float f32x4 __attribute__((ext_vector_type(4)));

#define BM 128
#define BN 128

typedef const __attribute__((address_space(1))) void gas_t;
typedef __attribute__((address_space(3))) void las_t;

__device__ __forceinline__ unsigned short f2bf(float f) {
  unsigned int u = __float_as_uint(f);
  u += 0x7FFFu + ((u >> 16) & 1u);   // round-to-nearest-even
  return (unsigned short)(u >> 16);
}

// packed max of two u32s holding 2x u16 (bf16 bit-order == numeric order for >=0)
__device__ __forceinline__ unsigned int pmaxu16(unsigned int a, unsigned int b) {
  unsigned int lo = ((a & 0xFFFFu) > (b & 0xFFFFu)) ? (a & 0xFFFFu) : (b & 0xFFFFu);
  unsigned int hi = ((a >> 16) > (b >> 16)) ? (a & 0xFFFF0000u) : (b & 0xFFFF0000u);
  return lo | hi;
}

// tanh via single v_exp_f32 + v_rcp_f32: tanh(x) = 1 - 2/(e^2x + 1).
__device__ __forceinline__ float fast_tanh(float x) {
  x = fminf(fmaxf(x, -10.f), 10.f);
  float t = __builtin_amdgcn_exp2f(x * 2.8853900817779268f);  // 2*log2(e)
  return 1.f - 2.f * __builtin_amdgcn_rcpf(t + 1.f);
}

// T1: XCD-aware bijective block remap (8 XCDs, requires nwg % 8 == 0).
// Launch index L -> work (L%8)*chunk + L/8: XCD k receives a CONTIGUOUS chunk
// of works, so neighbor tiles sharing operand panels hit the same L2.
__device__ __forceinline__ int xcd_swz(int bid, int nwg) {
  const int q = nwg >> 3;
  return (bid & 7) * q + (bid >> 3);
}

struct GemmP {
  const unsigned short* A;
  const unsigned short* Bm;
  void* C;
  const float* A2f;            // second A source for k >= kSplit: bf16 head-planes, max-reduced during staging
  // alt pointer set for merged launches: used when z >= zSplit
  const unsigned short* A_b;
  const unsigned short* Bm_b;
  void* C_b;
  const float* A2f_b;
  const float* mask_p;
  const float* mask_s;
  const float* bias;
  const float* bias_b;
  long long sAb, sAh, sBb, sBh, sCb, sCh;
  int lda, lda2, ldb, ldc, M, N, K, Hh, kSplit, zSplit, nbx, nby;
};

// ---------------------------------------------------------------------------
// Legacy 128x128 / 256-thread kernel (step 4 wp-part and step 5).
// TA: 0 = A is M x K row-major (lds-DMA staging, pitch 32); 1 = A stored K x M.
// EPI: 0 bf16 store; 1 tanh*mask bf16; 3 +bias,relu f32; 4 relu bf16 plane store.
// kSplit phase-2: A2f = 8 relu'd bf16 head-planes [b*8+h][512][128]; staging
// does the head-max in-register (integer max, bit-identical to pooled bf16).
template <int TA, int EPI>
__device__ __forceinline__ void gemm_body(const GemmP& p, int bx, int by, int bz, char* smem_) {
  constexpr int PA = (TA == 0) ? 32 : 40;
  constexpr int HSA = (TA == 0) ? 4096 : 5120;  // shorts per A half-tile
  unsigned short* As = (unsigned short*)smem_;
  unsigned short* Bs = (unsigned short*)(smem_ + 2 * HSA * 2);

  int z = bz;
  const unsigned short* Abase = p.A;
  const unsigned short* Bbase = p.Bm;
  void* Cvp = p.C;
  const float* A2f = p.A2f;
  const float* bias = p.bias;
  if (p.zSplit && z >= p.zSplit) {
    z -= p.zSplit;
    Abase = p.A_b; Bbase = p.Bm_b; Cvp = p.C_b; A2f = p.A2f_b; bias = p.bias_b;
  }
  const int zb = z / p.Hh, zh = z % p.Hh;
  const unsigned short* A = Abase + (size_t)zb * p.sAb + (size_t)zh * p.sAh;
  const unsigned short* B = Bbase + (size_t)zb * p.sBb + (size_t)zh * p.sBh;
  const int m0 = bx * BM, n0 = by * BN;
  const int tid = threadIdx.x;
  const int wid = tid >> 6, lane = tid & 63;
  const int wm = (wid >> 1) * 64, wn = (wid & 1) * 64;
  const int lrow = lane & 31;          // row within 32x32 frag
  const int lk8 = (lane >> 5) * 8;     // k-offset within 16-k chunk

  f32x16 acc[2][2] = {};

  const int dm = tid >> 2, dkg = tid & 3;

  auto mfma_block = [&]() {
#pragma unroll
    for (int h = 0; h < 2; ++h)
#pragma unroll
      for (int kc = 0; kc < 2; ++kc) {
        short8 af[2], bfv[2];
#pragma unroll
        for (int mt = 0; mt < 2; ++mt)
          af[mt] = *(const short8*)&As[h * HSA + (wm + mt * 32 + lrow) * PA + kc * 16 + lk8];
#pragma unroll
        for (int nt = 0; nt < 2; ++nt)
          bfv[nt] = *(const short8*)&Bs[h * 4096 + (wn + nt * 32 + lrow) * 32 + kc * 16 + lk8];
#pragma unroll
        for (int mt = 0; mt < 2; ++mt)
#pragma unroll
          for (int nt = 0; nt < 2; ++nt)
            acc[mt][nt] = __builtin_amdgcn_mfma_f32_32x32x16_bf16(af[mt], bfv[nt], acc[mt][nt], 0, 0, 0);
      }
  };
  auto stage_b = [&](int k0) {
#pragma unroll
    for (int h = 0; h < 2; ++h)
#pragma unroll
      for (int q = 0; q < 2; ++q) {
        const unsigned short* src = B + (size_t)(n0 + q * 64 + dm) * p.ldb + (k0 + h * 32 + dkg * 8);
        __builtin_amdgcn_global_load_lds((gas_t*)src,
                                         (las_t*)&Bs[h * 4096 + q * 2048 + wid * 512],
                                         16, 0, 0);
      }
  };

  const int nIter = p.K >> 6;
  const int nIter1 = p.kSplit ? (p.kSplit >> 6) : nIter;

  for (int it = 0; it < nIter1; ++it) {
    const int k0 = it << 6;
    if (TA == 0) {
#pragma unroll
      for (int h = 0; h < 2; ++h)
#pragma unroll
        for (int q = 0; q < 2; ++q) {
          const unsigned short* src = A + (size_t)(m0 + q * 64 + dm) * p.lda + (k0 + h * 32 + dkg * 8);
          __builtin_amdgcn_global_load_lds((gas_t*)src,
                                           (las_t*)&As[h * HSA + q * 2048 + wid * 512],
                                           16, 0, 0);
        }
    } else {
      const int kk = tid & 31, mg = (tid >> 5) << 4;
#pragma unroll
      for (int h = 0; h < 2; ++h) {
        const unsigned short* src = A + (size_t)(k0 + h * 32 + kk) * p.lda + (m0 + mg);
        uint4 v0 = *(const uint4*)src;
        uint4 v1 = *(const uint4*)(src + 8);
        unsigned short tmp[16];
        *(uint4*)&tmp[0] = v0;
        *(uint4*)&tmp[8] = v1;
#pragma unroll
        for (int j = 0; j < 16; ++j) As[h * HSA + (mg + j) * PA + kk] = tmp[j];
      }
    }
    stage_b(k0);
    __syncthreads();
    mfma_block();
    __syncthreads();
  }

  // phase 2 (TA=0, step 5): A from 8 relu'd bf16 head-planes with in-register
  // head-max during staging (integer max on non-negative bf16 == float max;
  // bit-identical to the old f32 pool + reduce_k pass).
  if (TA == 0 && p.kSplit) {
    const unsigned short* planes = (const unsigned short*)A2f;  // [b*8+h][512][128]
    for (int it = nIter1; it < nIter; ++it) {
      const int k0 = it << 6;
#pragma unroll
      for (int h2 = 0; h2 < 2; ++h2) {
        const int ko = k0 + h2 * 32 - p.kSplit;   // 0..127 within plane
#pragma unroll
        for (int q = 0; q < 2; ++q) {
          const int row = m0 + q * 64 + dm;       // = b*512 + x
          const unsigned int* s0 = (const unsigned int*)(planes
              + ((size_t)(((row >> 9) << 12) + (row & 511)) * 128 + ko + dkg * 8));
          uint4 mv = *(const uint4*)s0;
#pragma unroll
          for (int hh = 1; hh < 8; ++hh) {
            uint4 v = *(const uint4*)(s0 + (size_t)hh * 32768);   // head stride 512*128 shorts
            mv.x = pmaxu16(mv.x, v.x);
            mv.y = pmaxu16(mv.y, v.y);
            mv.z = pmaxu16(mv.z, v.z);
            mv.w = pmaxu16(mv.w, v.w);
          }
          *(uint4*)&As[h2 * HSA + (q * 64 + dm) * 32 + dkg * 8] = mv;
        }
      }
      stage_b(k0);
      __syncthreads();
      mfma_block();
      __syncthreads();
    }
  }

  unsigned short* Cu = (unsigned short*)Cvp + (size_t)zb * p.sCb + (size_t)zh * p.sCh;
  float* Cf = (float*)Cvp + (size_t)zb * p.sCb + (size_t)zh * p.sCh;

  const int rbase = 4 * (lane >> 5);

  float mp[2][16], ms[2];
  if constexpr (EPI == 1) {
#pragma unroll
    for (int mt = 0; mt < 2; ++mt)
#pragma unroll
      for (int reg = 0; reg < 16; ++reg) {
        const int rl = (reg & 3) + 8 * (reg >> 2) + rbase;
        mp[mt][reg] = p.mask_p[(size_t)zb * p.M + (m0 + wm + mt * 32 + rl)];
      }
#pragma unroll
    for (int nt = 0; nt < 2; ++nt)
      ms[nt] = p.mask_s[(size_t)zb * p.N + (n0 + wn + nt * 32 + lrow)];
  }
  if constexpr (EPI == 3) {
#pragma unroll
    for (int nt = 0; nt < 2; ++nt)
      ms[nt] = bias[n0 + wn + nt * 32 + lrow];
  }

#pragma unroll
  for (int mt = 0; mt < 2; ++mt) {
#pragma unroll
    for (int nt = 0; nt < 2; ++nt) {
      f32x16 a = acc[mt][nt];
#pragma unroll
      for (int reg = 0; reg < 16; ++reg) {
        const int rl = (reg & 3) + 8 * (reg >> 2) + rbase;
        const int grow = m0 + wm + mt * 32 + rl;
        const int gcol = n0 + wn + nt * 32 + lrow;
        const size_t idx = (size_t)grow * p.ldc + gcol;
        const float v = a[reg];
        if constexpr (EPI == 0) {
          Cu[idx] = f2bf(v);
        } else if constexpr (EPI == 1) {
          Cu[idx] = f2bf(fast_tanh(v) * (mp[mt][reg] * ms[nt]));
        } else if constexpr (EPI == 3) {
          Cf[idx] = fmaxf(v + ms[nt], 0.f);
        } else {
          // EPI == 4: relu, bf16 per-head plane store (head-max during step-5 staging)
          Cu[idx] = f2bf(fmaxf(v, 0.f));
        }
      }
    }
  }
}

template <int TA, int EPI>
__global__ __launch_bounds__(256) void gemm_k(GemmP p) {
  extern __shared__ char smem[];
  gemm_body<TA, EPI>(p, blockIdx.x, blockIdx.y, blockIdx.z, smem);
}

// ---------------------------------------------------------------------------
// gemm15: 256x128 tile / 512 threads / single-buffer — 3-blocks-per-CU design
// (r8-proven best: 62.4 us step-2, MfmaUtil 33.5%, no spill).
// 8 waves as 4(M) x 2(N), wave tile 64x64 = 4x4 frags -> acc[4][4] = 64 regs;
// total ~128 unified <= 170-reg cap at (512,3). LDS 48 KiB x 3 = 144K.
// Staging: global_load_lds width-16, LINEAR dest + inverse-swizzled GLOBAL
// source; reads XOR-swizzled byte ^= (row&7)<<4 (HW-verified 0 conflicts).
// r10 lesson: B-from-global (gemm17) regressed 62->103 us — B loads put L2
// latency on the serial path; lds-DMA staging hides it. Keep DMA for both.
// EPI: 0 = bf16 store; 1 = tanh*mask bf16; 4 = relu bf16 plane store.
template <int EPI>
__device__ __forceinline__ void gemm15_body(const GemmP& p, int bx, int by, int bz, char* smem_) {
  int z = bz;
  const unsigned short* Abase = p.A;
  const unsigned short* Bbase = p.Bm;
  void* Cvp = p.C;
  if (p.zSplit && z >= p.zSplit) {
    z -= p.zSplit;
    Abase = p.A_b; Bbase = p.Bm_b; Cvp = p.C_b;
  }
  const int zb = z / p.Hh, zh = z % p.Hh;
  const unsigned short* A = Abase + (size_t)zb * p.sAb + (size_t)zh * p.sAh;
  const unsigned short* B = Bbase + (size_t)zb * p.sBb + (size_t)zh * p.sBh;
  const int m0 = bx * 256, n0 = by * 128;
  const int tid = threadIdx.x;
  const int wid = tid >> 6, lane = tid & 63;
  const int wm = wid >> 1, wn = wid & 1;        // 4 x 2 wave grid, wave tile 64x64
  const int lrow = lane & 15, lhi = lane >> 4;  // MFMA 16x16x32 lane decomposition

  // staging source coords: LDS linear dest byte (seg s: s*8192 + tid*16) ->
  // row = s*64 + tid/8, col bytes = (tid&7)*16; source col = dest col ^ ((row&7)<<4)
  const int rr = tid >> 3;                              // 0..63
  const int cs = ((tid & 7) * 8) ^ ((rr & 7) << 3);     // source col, shorts

  // read-side swizzled lane offsets (bytes). row&7 == lrow&7 (frag rows 16-aligned)
  const int colx = (lhi * 16) ^ ((lrow & 7) << 4);
  const int offA = (wm * 64 + lrow) * 128 + colx;             // A region, ks=0
  const int offB = 32768 + (wn * 64 + lrow) * 128 + colx;     // B region, ks=0

  f32x4 acc[4][4] = {};

  const int nt = p.K >> 6;   // K-tiles of 64

  for (int t = 0; t < nt; ++t) {
    const int k0 = t << 6;
    // ---- stage tile t: A 4 segs x 64 rows (32KB), B 2 segs x 64 rows (16KB) ----
    const unsigned short* sa = A + (size_t)(m0 + rr) * p.lda + k0 + cs;
#pragma unroll
    for (int s = 0; s < 4; ++s)
      __builtin_amdgcn_global_load_lds((gas_t*)(sa + (size_t)(s * 64) * p.lda),
                                       (las_t*)(smem_ + s * 8192 + tid * 16), 16, 0, 0);
    const unsigned short* sb = B + (size_t)(n0 + rr) * p.ldb + k0 + cs;
#pragma unroll
    for (int s = 0; s < 2; ++s)
      __builtin_amdgcn_global_load_lds((gas_t*)(sb + (size_t)(s * 64) * p.ldb),
                                       (las_t*)(smem_ + 32768 + s * 8192 + tid * 16), 16, 0, 0);
    __syncthreads();   // vmcnt(0) drain; two co-resident blocks compute meanwhile

    short8 af[4], bv[4];
    // ---- phase 0 (ks = 0): all 16 MFMA of this wave's 64x64 tile
#pragma unroll
    for (int fn = 0; fn < 4; ++fn) bv[fn] = *(const short8*)(smem_ + offB + fn * 2048);
#pragma unroll
    for (int fm = 0; fm < 4; ++fm) af[fm] = *(const short8*)(smem_ + offA + fm * 2048);
    __builtin_amdgcn_s_setprio(1);
#pragma unroll
    for (int fm = 0; fm < 4; ++fm)
#pragma unroll
      for (int fn = 0; fn < 4; ++fn)
        acc[fm][fn] = __builtin_amdgcn_mfma_f32_16x16x32_bf16(af[fm], bv[fn], acc[fm][fn], 0, 0, 0);
    __builtin_amdgcn_s_setprio(0);

    // ---- phase 1 (ks = 1): ks=1 via ^64 on the swizzled byte col
#pragma unroll
    for (int fn = 0; fn < 4; ++fn) bv[fn] = *(const short8*)(smem_ + (offB ^ 64) + fn * 2048);
#pragma unroll
    for (int fm = 0; fm < 4; ++fm) af[fm] = *(const short8*)(smem_ + (offA ^ 64) + fm * 2048);
    __builtin_amdgcn_s_setprio(1);
#pragma unroll
    for (int fm = 0; fm < 4; ++fm)
#pragma unroll
      for (int fn = 0; fn < 4; ++fn)
        acc[fm][fn] = __builtin_amdgcn_mfma_f32_16x16x32_bf16(af[fm], bv[fn], acc[fm][fn], 0, 0, 0);
    __builtin_amdgcn_s_setprio(0);

    if (t + 1 < nt) __syncthreads();  // ds_reads done before next stage overwrites
  }

  // ---- epilogue ----
  unsigned short* Cu = (unsigned short*)Cvp + (size_t)zb * p.sCb + (size_t)zh * p.sCh;

  float ms[4];
  if constexpr (EPI == 1) {
#pragma unroll
    for (int fn = 0; fn < 4; ++fn)
      ms[fn] = p.mask_s[(size_t)zb * p.N + (n0 + wn * 64 + fn * 16 + lrow)];
  }

#pragma unroll
  for (int fm = 0; fm < 4; ++fm)
#pragma unroll
    for (int fn = 0; fn < 4; ++fn) {
      f32x4 a = acc[fm][fn];
      const int gcol = n0 + wn * 64 + fn * 16 + lrow;
#pragma unroll
      for (int reg = 0; reg < 4; ++reg) {
        const int grow = m0 + wm * 64 + fm * 16 + lhi * 4 + reg;
        const size_t idx = (size_t)grow * p.ldc + gcol;
        if constexpr (EPI == 0) {
          Cu[idx] = f2bf(a[reg]);
        } else if constexpr (EPI == 4) {
          Cu[idx] = f2bf(fmaxf(a[reg], 0.f));
        } else {
          const float mp = p.mask_p[(size_t)zb * p.M + grow];
          Cu[idx] = f2bf(fast_tanh(a[reg]) * (mp * ms[fn]));
        }
      }
    }
}

// flat-grid variant with XCD swizzle: decode bx/by/z from the remapped id
template <int EPI>
__global__ __launch_bounds__(512, 3) void gemm15_flat_k(GemmP p) {
  extern __shared__ char smem[];
  const int bid = xcd_swz(blockIdx.x, gridDim.x);
  const int per = p.nbx * p.nby;
  const int z = bid / per, r = bid % per;
  gemm15_body<EPI>(p, r % p.nbx, r / p.nbx, z, smem);
}

template <int E1, int E2>
__global__ __launch_bounds__(512, 3) void gemm15_pair_k(GemmP a, GemmP b, int nA) {
  extern __shared__ char smem[];
  int bid = xcd_swz(blockIdx.x, gridDim.x);   // T1: per-XCD contiguous work chunks
  if (bid < nA) {
    const int per = a.nbx * a.nby;
    const int z = bid / per, r = bid % per;
    gemm15_body<E1>(a, r % a.nbx, r / a.nbx, z, smem);
  } else {
    bid -= nA;
    const int per = b.nbx * b.nby;
    const int z = bid / per, r = bid % per;
    gemm15_body<E2>(b, r % b.nbx, r / b.nbx, z, smem);
  }
}

// ---- fused preamble: input cvt, 4 weight transposes ----
__device__ __forceinline__ void trans_body(const float* src, unsigned short* dst,
                                           int R, int C, int bx, int by, float (*tile)[33]) {
  const int r0 = by * 32, c0 = bx * 32;
  const int tx = threadIdx.x & 31, ty = threadIdx.x >> 5;  // 32 x 8
#pragma unroll
  for (int j = 0; j < 4; ++j)
    tile[ty + j * 8][tx] = src[(size_t)(r0 + ty + j * 8) * C + (c0 + tx)];
  __syncthreads();
#pragma unroll
  for (int j = 0; j < 4; ++j)
    dst[(size_t)(c0 + ty + j * 8) * R + (r0 + tx)] = f2bf(tile[tx][ty + j * 8]);
}

__global__ __launch_bounds__(256) void prep_k(const float* P, const float* S,
                                              unsigned short* Pbf, unsigned short* Sbf,
                                              const float* W_aff, unsigned short* WaT,
                                              const float* W_p, unsigned short* WpT,
                                              const float* W_s, unsigned short* WsT,
                                              const float* W_fp, unsigned short* WfpT,
                                              const float* W_fs, unsigned short* WfsT) {
  __shared__ float tile[32][33];
  const int bid = blockIdx.x;
  if (bid < 8192) {
    const int n4 = 1048576;  // 16*512*512/4
    int i = bid * 256 + threadIdx.x;
    const float4* s = (const float4*)P;
    ushort4* d = (ushort4*)Pbf;
    if (i >= n4) { i -= n4; s = (const float4*)S; d = (ushort4*)Sbf; }
    float4 v = s[i];
    ushort4 o;
    o.x = f2bf(v.x); o.y = f2bf(v.y); o.z = f2bf(v.z); o.w = f2bf(v.w);
    d[i] = o;
  } else if (bid < 10240) {
    const int l = bid - 8192;                      // 16x16 tiles x 8 heads
    const int z = l >> 8, r = l & 255;
    trans_body(W_aff + (size_t)z * 262144, WaT + (size_t)z * 262144, 512, 512,
               r & 15, r >> 4, tile);
  } else if (bid < 11264) {
    const int l = bid - 10240;                     // 32x16 tiles x 2
    const int z = l >> 9, r = l & 511;
    trans_body(z ? W_s : W_p, z ? WsT : WpT, 512, 1024, r & 31, r >> 5, tile);
  } else {
    const int l = bid - 11264;                     // 16x20 tiles x 2
    const int z = l / 320, r = l % 320;
    trans_body(z ? W_fs : W_fp, z ? WfsT : WfpT, 640, 512, r & 15, r >> 4, tile);
  }
}

extern "C" void kernel_launch(void* const* d_in, const int* in_sizes, int n_in,
                              void* d_out, int out_size, void* d_ws, size_t ws_size,
                              hipStream_t stream) {
  (void)in_sizes; (void)n_in; (void)out_size; (void)ws_size;
  const float* primary   = (const float*)d_in[0];
  const float* secondary = (const float*)d_in[1];
  const float* pmask     = (const float*)d_in[2];
  const float* smask     = (const float*)d_in[3];
  const float* W_aff     = (const float*)d_in[4];
  const float* W_p       = (const float*)d_in[5];
  const float* W_s       = (const float*)d_in[6];
  const float* W_fp      = (const float*)d_in[7];
  const float* b_fp      = (const float*)d_in[8];
  const float* W_fs      = (const float*)d_in[9];
  const float* b_fs      = (const float*)d_in[10];

  constexpr int Bb = 16, L = 512, Dd = 512, Hh = 8, HDd = 128, INNER = 1024, CAT = 640;
  constexpr int NT = Hh * Dd;                      // 4096
  constexpr long long LD = (long long)L * Dd;      // 262144
  constexpr long long LL = (long long)L * L;       // 262144

  // one-time: allow 48 KiB dynamic LDS on the gemm15-family kernels
  static bool s_attr = [] {
    hipFuncSetAttribute(reinterpret_cast<const void*>(&gemm15_pair_k<0, 0>),
                        hipFuncAttributeMaxDynamicSharedMemorySize, 49152);
    hipFuncSetAttribute(reinterpret_cast<const void*>(&gemm15_flat_k<1>),
                        hipFuncAttributeMaxDynamicSharedMemorySize, 49152);
    hipFuncSetAttribute(reinterpret_cast<const void*>(&gemm15_flat_k<4>),
                        hipFuncAttributeMaxDynamicSharedMemorySize, 49152);
    return true;
  }();
  (void)s_attr;

  char* base = (char*)d_ws;
  size_t off = 0;
  auto alloc = [&](size_t bytes) -> void* {
    void* r = base + off;
    off += (bytes + 255) & ~(size_t)255;
    return r;
  };

  unsigned short* Pbf   = (unsigned short*)alloc((size_t)Bb * L * Dd * 2);
  unsigned short* Sbf   = (unsigned short*)alloc((size_t)Bb * L * Dd * 2);
  unsigned short* WaT   = (unsigned short*)alloc((size_t)NT * Dd * 2);        // [h*512+f][e]
  unsigned short* WpT   = (unsigned short*)alloc((size_t)INNER * Dd * 2);     // [n][e]
  unsigned short* WsT   = (unsigned short*)alloc((size_t)INNER * Dd * 2);
  unsigned short* WfpT  = (unsigned short*)alloc((size_t)Dd * CAT * 2);       // [n][k]
  unsigned short* WfsT  = (unsigned short*)alloc((size_t)Dd * CAT * 2);
  unsigned short* psT   = (unsigned short*)alloc((size_t)Bb * INNER * L * 2); // [b][d][j]
  unsigned short* ppT   = (unsigned short*)alloc((size_t)Bb * INNER * L * 2); // [b][d][i]
  unsigned short* Tbuf  = (unsigned short*)alloc((size_t)Bb * L * NT * 2);    // [b*L+i][h*512+f]
  unsigned short* affb  = (unsigned short*)alloc((size_t)Bb * Hh * L * L * 2);

  // per-head relu'd planes (step 4 output): alias onto Tbuf (dead after step 3).
  // ws: [b][h][i][d] 16.8 MB ; wp: [b][h][j][d] 16.8 MB ; Tbuf is 64 MB.
  unsigned short* wsBuf = Tbuf;
  unsigned short* wpBuf = Tbuf + (size_t)Bb * Hh * L * HDd;

  // ---- 1) fused preamble ----
  prep_k<<<dim3(11904), dim3(256), 0, stream>>>(primary, secondary, Pbf, Sbf,
                                                W_aff, WaT, W_p, WpT, W_s, WsT,
                                                W_fp, WfpT, W_fs, WfsT);

  // ---- 2) Tbuf = P @ Waff(stacked)  ||  psT/ppT = (S@W_s)^T / (P@W_p)^T ----
  // gemm15: 256x128, 512 threads, single-buffer, 3 blocks/CU, XCD swizzle
  {
    GemmP a{};
    a.A = Pbf; a.lda = Dd;
    a.Bm = WaT; a.ldb = Dd;
    a.C = Tbuf; a.ldc = NT;
    a.M = Bb * L; a.N = NT; a.K = Dd; a.Hh = 1; a.nbx = 32; a.nby = 32;

    GemmP b{};
    b.A = WsT; b.lda = Dd; b.sAb = 0;
    b.Bm = Sbf; b.ldb = Dd; b.sBb = LD;
    b.C = psT; b.ldc = L; b.sCb = (long long)INNER * L;
    b.A_b = WpT; b.Bm_b = Pbf; b.C_b = ppT;
    b.M = INNER; b.N = L; b.K = Dd; b.Hh = 1; b.zSplit = Bb; b.nbx = 4; b.nby = 4;

    gemm15_pair_k<0, 0><<<dim3(1024 + 512), dim3(512), 49152, stream>>>(a, b, 1024);
  }

  // ---- 3) aff[b,h] = tanh(T[b,h] @ S_b^T) * mask  (flat grid + XCD swizzle) ----
  {
    GemmP g{};
    g.A = Tbuf; g.lda = NT; g.sAb = (long long)L * NT; g.sAh = Dd;
    g.Bm = Sbf; g.ldb = Dd; g.sBb = LD; g.sBh = 0;
    g.C = affb; g.ldc = L; g.sCb = (long long)Hh * LL; g.sCh = LL;
    g.mask_p = pmask; g.mask_s = smask;
    g.M = L; g.N = L; g.K = Dd; g.Hh = Hh; g.nbx = 2; g.nby = 4;
    gemm15_flat_k<1><<<dim3(2 * 4 * Bb * Hh), dim3(512), 49152, stream>>>(g);
  }

  // ---- 4a) ws = relu(aff @ psT^T) via gemm15 (fast A path, flat + swizzle) ----
  {
    GemmP a{};                       // ws: M=512(i), N=128(d), K=512(j) per (b,h)
    a.A = affb; a.lda = L; a.sAb = (long long)Hh * LL; a.sAh = LL;
    a.Bm = psT; a.ldb = L; a.sBb = (long long)INNER * L; a.sBh = (long long)HDd * L;
    a.C = wsBuf; a.ldc = HDd; a.sCb = (long long)Hh * L * HDd; a.sCh = (long long)L * HDd;
    a.M = L; a.N = HDd; a.K = L; a.Hh = Hh; a.nbx = 2; a.nby = 1;
    gemm15_flat_k<4><<<dim3(2 * Bb * Hh), dim3(512), 49152, stream>>>(a);
  }

  // ---- 4b) wp = relu(aff^T @ ppT^T) via legacy TA=1 (VALU-transpose A) ----
  {
    GemmP b{};
    b.A = affb; b.lda = L; b.sAb = (long long)Hh * LL; b.sAh = LL;
    b.Bm = ppT; b.ldb = L; b.sBb = (long long)INNER * L; b.sBh = (long long)HDd * L;
    b.C = wpBuf; b.ldc = HDd; b.sCb = (long long)Hh * L * HDd; b.sCh = (long long)L * HDd;
    b.M = L; b.N = HDd; b.K = L; b.Hh = Hh;
    gemm_k<1, 4><<<dim3(4, 1, Bb * Hh), dim3(256), 36864, stream>>>(b);
  }

  // ---- 5) merged output FFNs; A2 = bf16 head-planes, head-max during staging ----
  {
    GemmP g{};
    g.A = Pbf; g.lda = Dd;
    g.A2f = (const float*)wsBuf; g.lda2 = HDd; g.kSplit = Dd;
    g.Bm = WfpT; g.ldb = CAT;
    g.C = d_out; g.ldc = Dd;
    g.bias = b_fp;
    g.A_b = Sbf; g.A2f_b = (const float*)wpBuf; g.Bm_b = WfsT;
    g.C_b = (float*)d_out + (size_t)Bb * L * Dd;
    g.bias_b = b_fs;
    g.M = Bb * L; g.N = Dd; g.K = CAT; g.Hh = 1; g.zSplit = 1;
    gemm_k<0, 3><<<dim3(64, 4, 2), dim3(256), 32768, stream>>>(g);
  }
}